// Round 10
// baseline (241.594 us; speedup 1.0000x reference)
//
#include <hip/hip_runtime.h>
#include <math.h>

// PathPreservingNetwork — factored-class + bf16x3 MFMA, R13 (resubmit; R9's
// bench was an infra failure — container died before compile/run).
// R13 = R12 with the two R5-proven epilogue fusions:
//  - ns (C5 row sum-of-squares) computed in L4's epilogue via shfl+atomicAdd
//    (kills the 16MB C5 re-read; L5 dispatch is a plain 496-block GEMM).
//  - dotv/nrmv computed in L5's epilogue the same way (kills stats5_k and
//    its 8MB Y5 re-read).
//  - transW z=6 slice zeroes ns/dotv/nrmv each replay.
// Atomic jitter is prune-safe: duplicate keys share one memory cell
// (identical bits -> index tie-break); distinct-class gaps O(1) >> jitter.
// R5 passed with exactly these fusions. 13 dispatches.
// Locked lessons:
//  - R5: __threadfence split-K fusion = 4x loss (per-XCD L2 wb/inv).
//  - R8: grids < ~1.5 blocks/CU are latency-starved (64x128 tile: 312us).
//  - R9: >4 in-flight uint4 prefetch regs spill (WRITE_SIZE 116MB).
//  - R10: 32x64 tile halves MFMA:LDS ratio -> 251us. 64x64 optimum.
//  - R11: replicated per-block rank loops beat dispatch savings. Prune
//    stays centralized in prune45_k.

using s8v = __attribute__((ext_vector_type(8))) short;
using f4v = __attribute__((ext_vector_type(4))) float;

__device__ __forceinline__ float bf2f(short b) {
  unsigned u = ((unsigned)(unsigned short)b) << 16;
  return __builtin_bit_cast(float, u);
}
__device__ __forceinline__ short f2bf(float f) {
  unsigned u = __builtin_bit_cast(unsigned, f);
  u = (u + 0x7FFFu + ((u >> 16) & 1u)) >> 16;
  return (short)u;
}
__device__ __forceinline__ void split_store(float f, short* hi, short* lo) {
  short h = f2bf(f);
  *hi = h;
  *lo = f2bf(f - bf2f(h));
}

// Transpose+split all six W (1024 x N fp32) -> (N x 1024 bf16 hi/lo).
// z==6 slice: pack x into hi/lo bf16 (blocks 0-127) + zero ns/dotv/nrmv
// (blocks 128+; re-zeroed in-stream every graph replay).
struct TWArgs {
  const float* W[6];
  short* Th[6];
  short* Tl[6];
};
__global__ void __launch_bounds__(256)
transW_all(TWArgs a, const float* __restrict__ x, short* __restrict__ A0h,
           short* __restrict__ A0l, float4* __restrict__ zreg) {
  __shared__ float tile[64][65];
  const int t = threadIdx.x;
  if (blockIdx.z == 6) {
    const int bf = blockIdx.y * 16 + blockIdx.x;
    if (bf < 128) {
      int i = (bf * 256 + t) * 4;
      float4 v = *(const float4*)&x[i];
      short4 h, l;
      h.x = f2bf(v.x); l.x = f2bf(v.x - bf2f(h.x));
      h.y = f2bf(v.y); l.y = f2bf(v.y - bf2f(h.y));
      h.z = f2bf(v.z); l.z = f2bf(v.z - bf2f(h.z));
      h.w = f2bf(v.w); l.w = f2bf(v.w - bf2f(h.w));
      *(short4*)&A0h[i] = h;
      *(short4*)&A0l[i] = l;
    } else {
      int flat = (bf - 128) * 256 + t;
      if (flat < 2976) {  // 47616 B: ns + dotv + nrmv (3968 f32 each)
        float4 zz = {0.f, 0.f, 0.f, 0.f};
        zreg[flat] = zz;
      }
    }
    return;
  }
  const int z = blockIdx.z;
  const int N = (z == 5) ? 512 : 1024;
  const int n0 = blockIdx.x * 64, k0 = blockIdx.y * 64;
  if (n0 >= N) return;
  const float* __restrict__ W = a.W[z];
  short* __restrict__ Th = a.Th[z];
  short* __restrict__ Tl = a.Tl[z];
  const int r = t >> 4, c4 = (t & 15) * 4;
#pragma unroll
  for (int i = 0; i < 4; ++i) {
    int rr = r + 16 * i;
    float4 v = *(const float4*)&W[(size_t)(k0 + rr) * N + n0 + c4];
    tile[rr][c4 + 0] = v.x;
    tile[rr][c4 + 1] = v.y;
    tile[rr][c4 + 2] = v.z;
    tile[rr][c4 + 3] = v.w;
  }
  __syncthreads();
#pragma unroll
  for (int i = 0; i < 4; ++i) {
    int n = r + 16 * i;
    short4 h, l;
    float f0 = tile[c4 + 0][n], f1 = tile[c4 + 1][n];
    float f2 = tile[c4 + 2][n], f3 = tile[c4 + 3][n];
    h.x = f2bf(f0); l.x = f2bf(f0 - bf2f(h.x));
    h.y = f2bf(f1); l.y = f2bf(f1 - bf2f(h.y));
    h.z = f2bf(f2); l.z = f2bf(f2 - bf2f(h.z));
    h.w = f2bf(f3); l.w = f2bf(f3 - bf2f(h.w));
    size_t o = (size_t)(n0 + n) * 1024 + k0 + c4;
    *(short4*)&Th[o] = h;
    *(short4*)&Tl[o] = l;
  }
}

// ------------------------------------------------------------- MFMA GEMM ----
// R7 body: block tile 64x64, 4 waves 2x2, wave tile 32x32 (12 MFMA/stage),
// BK=32, BKP=40 pad (<=2-way LDS conflicts = free), register prefetch.
// MODE 1: fused L4 epilogue (tanh expansion, hi/lo out) + ns atomics (aux0).
// MODE 2: raw fp32 out + dot(bias,row)/||row||^2 atomics (aux0/aux1).
// MODE 3: split-K partial: Of[(bz*R + rr)*N + col] = acc.
template <int MODE, int D, int KS>
__device__ __forceinline__ void gemm_body(
    int bx, int by, int bz, int R, const short* __restrict__ Ah,
    const short* __restrict__ Al, const short* __restrict__ Bh,
    const short* __restrict__ Bl, const float* __restrict__ bias,
    short* __restrict__ Oh, short* __restrict__ Ol, float* __restrict__ Of,
    float* __restrict__ aux0, float* __restrict__ aux1, int N, int Dn) {
  constexpr int KC = 1024 / KS;
  constexpr int BKP = 40;
  __shared__ short As_h[64 * BKP], As_l[64 * BKP];
  __shared__ short Bs_h[64 * BKP], Bs_l[64 * BKP];
  const int t = threadIdx.x;
  const int row0 = by * 64;
  const int col0 = bx * 64;
  const int kb = bz * KC;
  const int sr = t >> 2, sko = (t & 3) * 8;
  const short* Ahp = Ah + (size_t)(row0 + sr) * 1024 + kb + sko;
  const short* Alp = Al + (size_t)(row0 + sr) * 1024 + kb + sko;
  const short* Bhp = Bh + (size_t)(col0 + sr) * 1024 + kb + sko;
  const short* Blp = Bl + (size_t)(col0 + sr) * 1024 + kb + sko;
  const int w = t >> 6, lane = t & 63;
  const int l16 = lane & 15, q = lane >> 4;
  const int wm0 = (w & 1) * 32, wn0 = (w >> 1) * 32;
  const int abase = (wm0 + l16) * BKP + q * 8;
  const int bbase = (wn0 + l16) * BKP + q * 8;
  f4v acc[2][2];
#pragma unroll
  for (int i = 0; i < 2; ++i)
#pragma unroll
    for (int j = 0; j < 2; ++j) acc[i][j] = (f4v){0.f, 0.f, 0.f, 0.f};
  uint4 rah = *(const uint4*)(Ahp);
  uint4 ral = *(const uint4*)(Alp);
  uint4 rbh = *(const uint4*)(Bhp);
  uint4 rbl = *(const uint4*)(Blp);
  for (int k0 = 0; k0 < KC; k0 += 32) {
    __syncthreads();
    *(uint4*)&As_h[sr * BKP + sko] = rah;
    *(uint4*)&As_l[sr * BKP + sko] = ral;
    *(uint4*)&Bs_h[sr * BKP + sko] = rbh;
    *(uint4*)&Bs_l[sr * BKP + sko] = rbl;
    if (k0 + 32 < KC) {  // prefetch next slab; waits land before next LDS-write
      rah = *(const uint4*)(Ahp + k0 + 32);
      ral = *(const uint4*)(Alp + k0 + 32);
      rbh = *(const uint4*)(Bhp + k0 + 32);
      rbl = *(const uint4*)(Blp + k0 + 32);
    }
    __syncthreads();
    s8v ah[2], al[2], bh[2], bl[2];
#pragma unroll
    for (int mt = 0; mt < 2; ++mt) {
      ah[mt] = *(const s8v*)&As_h[abase + mt * 16 * BKP];
      al[mt] = *(const s8v*)&As_l[abase + mt * 16 * BKP];
    }
#pragma unroll
    for (int nt = 0; nt < 2; ++nt) {
      bh[nt] = *(const s8v*)&Bs_h[bbase + nt * 16 * BKP];
      bl[nt] = *(const s8v*)&Bs_l[bbase + nt * 16 * BKP];
    }
#pragma unroll
    for (int mt = 0; mt < 2; ++mt)
#pragma unroll
      for (int nt = 0; nt < 2; ++nt) {
        acc[mt][nt] = __builtin_amdgcn_mfma_f32_16x16x32_bf16(
            ah[mt], bh[nt], acc[mt][nt], 0, 0, 0);
        acc[mt][nt] = __builtin_amdgcn_mfma_f32_16x16x32_bf16(
            ah[mt], bl[nt], acc[mt][nt], 0, 0, 0);
        acc[mt][nt] = __builtin_amdgcn_mfma_f32_16x16x32_bf16(
            al[mt], bh[nt], acc[mt][nt], 0, 0, 0);
      }
  }

  if (MODE == 1) {
    // L4: tanh expansion + per-row sum-of-squares atomics into aux0 (=ns).
    const float bc0 = bias[col0 + wn0 + l16];
    const float bc1 = bias[col0 + wn0 + 16 + l16];
#pragma unroll
    for (int mt = 0; mt < 2; ++mt) {
#pragma unroll
      for (int r = 0; r < 4; ++r) {
        const int rr = row0 + wm0 + mt * 16 + q * 4 + r;
        const int b = rr / D, u = rr - b * D;
        const size_t obr = (size_t)(b * Dn) * N;
        const size_t omr = obr + (size_t)(1 + 2 * u) * N;
        const size_t opr = obr + (size_t)(2 + 2 * u) * N;
        float sm = 0.f, sp = 0.f, sb = 0.f;
#pragma unroll
        for (int nt = 0; nt < 2; ++nt) {
          const int gcol = col0 + wn0 + nt * 16 + l16;
          const float bc = nt ? bc1 : bc0;
          const float v = acc[mt][nt][r];
          float tm = tanhf(bc - v), tp = tanhf(bc + v);
          split_store(tm, &Oh[omr + gcol], &Ol[omr + gcol]);
          split_store(tp, &Oh[opr + gcol], &Ol[opr + gcol]);
          sm = fmaf(tm, tm, sm);
          sp = fmaf(tp, tp, sp);
          if (u == 0) {
            float tb = tanhf(bc);
            split_store(tb, &Oh[obr + gcol], &Ol[obr + gcol]);
            sb = fmaf(tb, tb, sb);
          }
        }
#pragma unroll
        for (int d = 1; d < 16; d <<= 1) {
          sm += __shfl_xor(sm, d);
          sp += __shfl_xor(sp, d);
          sb += __shfl_xor(sb, d);
        }
        if (l16 == 0) {
          atomicAdd(&aux0[b * Dn + 1 + 2 * u], sm);
          atomicAdd(&aux0[b * Dn + 2 + 2 * u], sp);
          if (u == 0) atomicAdd(&aux0[b * Dn], sb);
        }
      }
    }
    return;
  }

  if (MODE == 2) {
    // L5: raw fp32 out + dot(b5,row)/||row||^2 atomics (aux0/aux1).
    const float bc0 = bias[col0 + wn0 + l16];
    const float bc1 = bias[col0 + wn0 + 16 + l16];
#pragma unroll
    for (int mt = 0; mt < 2; ++mt) {
#pragma unroll
      for (int r = 0; r < 4; ++r) {
        const int rr = row0 + wm0 + mt * 16 + q * 4 + r;
        float sd = 0.f, sn = 0.f;
#pragma unroll
        for (int nt = 0; nt < 2; ++nt) {
          const int gcol = col0 + wn0 + nt * 16 + l16;
          const float bc = nt ? bc1 : bc0;
          const float v = acc[mt][nt][r];
          Of[(size_t)rr * N + gcol] = v;
          sd = fmaf(bc, v, sd);
          sn = fmaf(v, v, sn);
        }
#pragma unroll
        for (int d = 1; d < 16; d <<= 1) {
          sd += __shfl_xor(sd, d);
          sn += __shfl_xor(sn, d);
        }
        if (l16 == 0) {
          atomicAdd(&aux0[rr], sd);
          atomicAdd(&aux1[rr], sn);
        }
      }
    }
    return;
  }

  // MODE 3: split-K partial write (combine in a separate dispatch — the
  // kernel-launch boundary is the cheap XCD-coherence point).
#pragma unroll
  for (int nt = 0; nt < 2; ++nt) {
    int gcol = col0 + wn0 + nt * 16 + l16;
#pragma unroll
    for (int mt = 0; mt < 2; ++mt)
#pragma unroll
      for (int r = 0; r < 4; ++r) {
        int rr = row0 + wm0 + mt * 16 + q * 4 + r;
        Of[((size_t)bz * R + rr) * N + gcol] = acc[mt][nt][r];
      }
  }
}

template <int MODE, int D, int KS>
__global__ void __launch_bounds__(256, 2)
mfma_gemm(const short* __restrict__ Ah, const short* __restrict__ Al,
          const short* __restrict__ Bh, const short* __restrict__ Bl,
          const float* __restrict__ bias, short* __restrict__ Oh,
          short* __restrict__ Ol, float* __restrict__ Of,
          float* __restrict__ aux0, float* __restrict__ aux1, int N, int Dn) {
  gemm_body<MODE, D, KS>(blockIdx.x, blockIdx.y, blockIdx.z,
                         (int)gridDim.y << 6, Ah, Al, Bh, Bl, bias, Oh, Ol,
                         Of, aux0, aux1, N, Dn);
}

// Combine split-K partials, layer 0: out = tanh(bias + sum) -> hi/lo.
template <int KS>
__global__ void __launch_bounds__(256)
comb0_hl(const float* __restrict__ P, const float* __restrict__ bias,
         short* __restrict__ Oh, short* __restrict__ Ol, int R, int N) {
  int i = blockIdx.x * 256 + threadIdx.x;
  int n4 = N >> 2;
  int r = i / n4, c4 = (i - r * n4) * 4;
  float4 y = *(const float4*)&P[(size_t)r * N + c4];
  size_t stride = (size_t)R * N;
#pragma unroll
  for (int ks = 1; ks < KS; ++ks) {
    const float4 p = *(const float4*)&P[ks * stride + (size_t)r * N + c4];
    y.x += p.x; y.y += p.y; y.z += p.z; y.w += p.w;
  }
  float4 bc = *(const float4*)(bias + c4);
  float t0 = tanhf(bc.x + y.x), t1 = tanhf(bc.y + y.y);
  float t2 = tanhf(bc.z + y.z), t3 = tanhf(bc.w + y.w);
  short4 h, l;
  h.x = f2bf(t0); l.x = f2bf(t0 - bf2f(h.x));
  h.y = f2bf(t1); l.y = f2bf(t1 - bf2f(h.y));
  h.z = f2bf(t2); l.z = f2bf(t2 - bf2f(h.z));
  h.w = f2bf(t3); l.w = f2bf(t3 - bf2f(h.w));
  *(short4*)&Oh[(size_t)r * N + c4] = h;
  *(short4*)&Ol[(size_t)r * N + c4] = l;
}

// Combine split-K partials, layers 1..3: rows b*Dn+1+2u (tanh(b-y)) and
// b*Dn+2+2u (tanh(b+y)); zero row tanh(b) at u==0. hi/lo out.
template <int KS, int D>
__global__ void __launch_bounds__(256)
comb1_hl(const float* __restrict__ P, const float* __restrict__ bias,
         short* __restrict__ Oh, short* __restrict__ Ol, int R, int N,
         int Dn) {
  int i = blockIdx.x * 256 + threadIdx.x;
  int n4 = N >> 2;
  int r = i / n4, c4 = (i - r * n4) * 4;
  int b = r / D, u = r - b * D;
  float4 y = *(const float4*)&P[(size_t)r * N + c4];
  size_t stride = (size_t)R * N;
#pragma unroll
  for (int ks = 1; ks < KS; ++ks) {
    const float4 p = *(const float4*)&P[ks * stride + (size_t)r * N + c4];
    y.x += p.x; y.y += p.y; y.z += p.z; y.w += p.w;
  }
  float4 bc = *(const float4*)(bias + c4);
  size_t ob = (size_t)(b * Dn) * N + c4;
  size_t om = ob + (size_t)(1 + 2 * u) * N;
  size_t op = ob + (size_t)(2 + 2 * u) * N;
  {
    float t0 = tanhf(bc.x - y.x), t1 = tanhf(bc.y - y.y);
    float t2 = tanhf(bc.z - y.z), t3 = tanhf(bc.w - y.w);
    short4 h, l;
    h.x = f2bf(t0); l.x = f2bf(t0 - bf2f(h.x));
    h.y = f2bf(t1); l.y = f2bf(t1 - bf2f(h.y));
    h.z = f2bf(t2); l.z = f2bf(t2 - bf2f(h.z));
    h.w = f2bf(t3); l.w = f2bf(t3 - bf2f(h.w));
    *(short4*)&Oh[om] = h;
    *(short4*)&Ol[om] = l;
  }
  {
    float t0 = tanhf(bc.x + y.x), t1 = tanhf(bc.y + y.y);
    float t2 = tanhf(bc.z + y.z), t3 = tanhf(bc.w + y.w);
    short4 h, l;
    h.x = f2bf(t0); l.x = f2bf(t0 - bf2f(h.x));
    h.y = f2bf(t1); l.y = f2bf(t1 - bf2f(h.y));
    h.z = f2bf(t2); l.z = f2bf(t2 - bf2f(h.z));
    h.w = f2bf(t3); l.w = f2bf(t3 - bf2f(h.w));
    *(short4*)&Oh[op] = h;
    *(short4*)&Ol[op] = l;
  }
  if (u == 0) {
    float t0 = tanhf(bc.x), t1 = tanhf(bc.y);
    float t2 = tanhf(bc.z), t3 = tanhf(bc.w);
    short4 h, l;
    h.x = f2bf(t0); l.x = f2bf(t0 - bf2f(h.x));
    h.y = f2bf(t1); l.y = f2bf(t1 - bf2f(h.y));
    h.z = f2bf(t2); l.z = f2bf(t2 - bf2f(h.z));
    h.w = f2bf(t3); l.w = f2bf(t3 - bf2f(h.w));
    *(short4*)&Oh[ob] = h;
    *(short4*)&Ol[ob] = l;
  }
}

// Merged prune: per-batch 243->128 (layer-4 classes) then 384->128 (final).
// ||b5||^2 computed in-block (R4 stats5's exact reduction order).
__global__ void __launch_bounds__(384)
prune45_k(const float* __restrict__ ns, const float* __restrict__ dotv,
          const float* __restrict__ nrmv, const float* __restrict__ b5,
          int* __restrict__ kept4, int* __restrict__ kept5) {
  const int b = blockIdx.x, t = threadIdx.x;
  __shared__ float nss[31];
  __shared__ float rb[256];
  __shared__ float keyA[243];
  __shared__ int cls[243];
  __shared__ int k4s[128];
  __shared__ float pns[128];
  __shared__ float keyB[384];
  if (t < 31) nss[t] = ns[b * 31 + t];
  if (t < 256) {
    float a = b5[t], c = b5[t + 256];
    rb[t] = fmaf(a, a, 0.f);
    rb[t] = fmaf(c, c, rb[t]);
  }
  __syncthreads();
  for (int off = 128; off; off >>= 1) {
    if (t < off) rb[t] += rb[t + off];
    __syncthreads();
  }
  const float nb5 = rb[0];
  if (t < 243) {
    int j = t / 3, t4 = t - 3 * j;
    int d0 = j / 27, d1 = (j / 9) % 3, d2 = (j / 3) % 3, d3 = j % 3;
    int u = 0;
    u = (d0 == 1) ? 0 : (1 + 2 * u + (d0 == 2));
    u = (d1 == 1) ? 0 : (1 + 2 * u + (d1 == 2));
    u = (d2 == 1) ? 0 : (1 + 2 * u + (d2 == 2));
    u = (d3 == 1) ? 0 : (1 + 2 * u + (d3 == 2));
    cls[t] = u;
    keyA[t] = (t4 == 1) ? 0.f : nss[u];
  }
  __syncthreads();
  if (t < 243) {
    float k = keyA[t];
    int rank = 0;
    for (int e = 0; e < 243; ++e) {
      float ke = keyA[e];
      rank += (ke > k) || (ke == k && e < t);
    }
    if (rank < 128) {
      int t4 = t - 3 * (t / 3);
      int kv = (cls[t] << 1) | (t4 == 2 ? 1 : 0);
      k4s[rank] = kv;
      kept4[b * 128 + rank] = kv;
    }
  }
  __syncthreads();
  if (t < 128) {
    int k4 = k4s[t];
    int c = k4 >> 1;
    float s = (k4 & 1) ? 1.f : -1.f;
    pns[t] = nb5 + nrmv[b * 31 + c] + s * 2.f * dotv[b * 31 + c];
  }
  __syncthreads();
  const int m = t / 3, tt = t - 3 * m;
  keyB[t] = (tt == 1) ? 0.f : pns[m];
  __syncthreads();
  float k = keyB[t];
  int rank = 0;
  for (int e = 0; e < 384; ++e) {
    float ke = keyB[e];
    rank += (ke > k) || (ke == k && e < t);
  }
  if (rank < 128) kept5[b * 128 + rank] = (m << 1) | (tt == 2 ? 1 : 0);
}

// Final data (B,512,128) + argmax-|.| output (B,512).
__global__ void __launch_bounds__(256)
finalize_k(const float* __restrict__ Y5, const float* __restrict__ b5,
           const int* __restrict__ kept4, const int* __restrict__ kept5,
           float* __restrict__ out, float* __restrict__ dataout) {
  const int b = blockIdx.y;
  const int o0 = blockIdx.x * 64;
  __shared__ float Ys[31][65];
  __shared__ float bias_s[64];
  __shared__ float vt[64][130];
  __shared__ float ra[64][4];
  __shared__ float rv[64][4];
  const int t = threadIdx.x;
  for (int idx = t; idx < 31 * 64; idx += 256) {
    int c = idx >> 6, o = idx & 63;
    Ys[c][o] = Y5[((size_t)b * 31 + c) * 512 + o0 + o];
  }
  if (t < 64) bias_s[t] = b5[o0 + t];
  const int rr = t & 127, oh = t >> 7;
  int k5 = kept5[b * 128 + rr];
  int m = k5 >> 1;
  float sig = (k5 & 1) ? 1.f : -1.f;
  int k4 = kept4[b * 128 + m];
  int cc = k4 >> 1;
  float s4 = (k4 & 1) ? 1.f : -1.f;
  float afac = sig * s4;
  __syncthreads();
#pragma unroll
  for (int ol = 0; ol < 32; ++ol) {
    int o = oh * 32 + ol;
    float v = sig * bias_s[o] + afac * Ys[cc][o];
    dataout[((size_t)b * 512 + o0 + o) * 128 + rr] = v;
    vt[o][rr] = v;
  }
  __syncthreads();
  int o = t >> 2, q = t & 3;
  float bestv = vt[o][q * 32];
  float besta = fabsf(bestv);
  for (int i = 1; i < 32; ++i) {
    float v = vt[o][q * 32 + i];
    float a = fabsf(v);
    if (a > besta) {
      besta = a;
      bestv = v;
    }
  }
  ra[o][q] = besta;
  rv[o][q] = bestv;
  __syncthreads();
  if (t < 64) {
    float ba = ra[t][0], bv = rv[t][0];
#pragma unroll
    for (int qq = 1; qq < 4; ++qq) {
      if (ra[t][qq] > ba) {
        ba = ra[t][qq];
        bv = rv[t][qq];
      }
    }
    out[(size_t)b * 512 + o0 + t] = bv;
  }
}

extern "C" void kernel_launch(void* const* d_in, const int* in_sizes, int n_in,
                              void* d_out, int out_size, void* d_ws,
                              size_t ws_size, hipStream_t stream) {
  const float* x = (const float*)d_in[0];
  const float* Wt[6];
  const float* bs[6];
  for (int i = 0; i < 6; ++i) {
    Wt[i] = (const float*)d_in[1 + 2 * i];
    bs[i] = (const float*)d_in[2 + 2 * i];
  }
  char* base = (char*)d_ws;
  // Byte-offset layout. Lifetime-disjoint aliases:
  //   PA (split-K partials L0-L2) over C4h/C4l (written first at L3-comb);
  //     L0/L1 KS=8 partials = 4 MB, L2 KS=4 = 6.3 MB, region is 7.86 MB.
  //   PB (split-K partials L3)    over W0/W1   (dead after L1)
  //   C5h over W0..W1, C5l over W2..W3 (dead after L3)
  //   Y5 over C1..C4 (dead after L4)
  short* A0h = (short*)(base + 0);
  short* A0l = (short*)(base + 262144);
  short* Wh[6], *Wl[6];
  {
    size_t off = 524288;
    for (int i = 0; i < 6; ++i) {
      size_t sz = (i < 5) ? 2097152 : 1048576;
      Wh[i] = (short*)(base + off);
      Wl[i] = (short*)(base + off + sz);
      off += 2 * sz;
    }
  }
  short* C1h = (short*)(base + 23592960), *C1l = (short*)(base + 23855104);
  short* C2h = (short*)(base + 24117248), *C2l = (short*)(base + 24903680);
  short* C3h = (short*)(base + 25690112), *C3l = (short*)(base + 27525120);
  short* C4h = (short*)(base + 29360128), *C4l = (short*)(base + 33292288);
  short* C5h = (short*)(base + 524288);
  short* C5l = (short*)(base + 8912896);
  float* PA = (float*)(base + 29360128);  // L0/L1 KS=8: 4 MB; L2 KS=4: 6.3 MB
  float* PB = (float*)(base + 524288);    // 7.34 MB (L3 KS=2)
  float* Y5 = (float*)(base + 23592960);
  // Zero region (cleared each replay by transW_all z==6 slice):
  char* zb = base + 37224448;
  float* ns = (float*)zb;                 // 3968 f32
  float* dotv = (float*)(zb + 15872);     // 3968 f32
  float* nrmv = (float*)(zb + 31744);     // 3968 f32
  int* kept4 = (int*)(zb + 47616);
  int* kept5 = (int*)(zb + 113152);
  float* outp = (float*)d_out;
  float* dataout = outp + 128 * 512;

  dim3 blk(256);
  TWArgs twa;
  for (int i = 0; i < 6; ++i) {
    twa.W[i] = Wt[i];
    twa.Th[i] = Wh[i];
    twa.Tl[i] = Wl[i];
  }
  // Transpose W + pack x + zero ns/dotv/nrmv, one launch.
  transW_all<<<dim3(16, 16, 7), blk, 0, stream>>>(twa, x, A0h, A0l,
                                                  (float4*)zb);
  // L0: x -> C1 (split-K 8, 256 blocks)
  mfma_gemm<3, 1, 8><<<dim3(16, 2, 8), blk, 0, stream>>>(
      A0h, A0l, Wh[0], Wl[0], nullptr, nullptr, nullptr, PA, nullptr, nullptr,
      1024, 0);
  comb0_hl<8><<<dim3(128), blk, 0, stream>>>(PA, bs[0], C1h, C1l, 128, 1024);
  // L1: C1 -> C2 (split-K 8, 256 blocks)
  mfma_gemm<3, 1, 8><<<dim3(16, 2, 8), blk, 0, stream>>>(
      C1h, C1l, Wh[1], Wl[1], nullptr, nullptr, nullptr, PA, nullptr, nullptr,
      1024, 0);
  comb1_hl<8, 1><<<dim3(128), blk, 0, stream>>>(PA, bs[1], C2h, C2l, 128, 1024,
                                                3);
  // L2: C2 (384) -> C3 (split-K 4)
  mfma_gemm<3, 3, 4><<<dim3(16, 6, 4), blk, 0, stream>>>(
      C2h, C2l, Wh[2], Wl[2], nullptr, nullptr, nullptr, PA, nullptr, nullptr,
      1024, 0);
  comb1_hl<4, 3><<<dim3(384), blk, 0, stream>>>(PA, bs[2], C3h, C3l, 384, 1024,
                                                7);
  // L3: C3 (896) -> C4 (split-K 2, partials over dead W0/W1)
  mfma_gemm<3, 7, 2><<<dim3(16, 14, 2), blk, 0, stream>>>(
      C3h, C3l, Wh[3], Wl[3], nullptr, nullptr, nullptr, PB, nullptr, nullptr,
      1024, 0);
  comb1_hl<2, 7><<<dim3(896), blk, 0, stream>>>(PB, bs[3], C4h, C4l, 896, 1024,
                                                15);
  // L4: C4 (1920) -> C5 (3968), fused epilogue + ns atomics
  mfma_gemm<1, 15, 1><<<dim3(16, 30), blk, 0, stream>>>(
      C4h, C4l, Wh[4], Wl[4], bs[4], C5h, C5l, nullptr, ns, nullptr, 1024, 31);
  // L5: C5 -> Y5 raw fp32 (3968 x 512) + dot/nrm atomics
  mfma_gemm<2, 31, 1><<<dim3(8, 62), blk, 0, stream>>>(
      C5h, C5l, Wh[5], Wl[5], bs[5], nullptr, nullptr, Y5, dotv, nrmv, 512, 0);
  // Merged prune (243->128 then 384->128, per batch)
  prune45_k<<<dim3(128), dim3(384), 0, stream>>>(ns, dotv, nrmv, bs[5], kept4,
                                                 kept5);
  finalize_k<<<dim3(8, 128), blk, 0, stream>>>(Y5, bs[5], kept4, kept5, outp,
                                               dataout);
}

// Round 11
// 231.142 us; speedup vs baseline: 1.0452x; 1.0452x over previous
//
#include <hip/hip_runtime.h>
#include <math.h>

// PathPreservingNetwork — factored-class + bf16x3 MFMA, R14.
// R14 = R12's structure + R13's L5-ONLY stats fusion:
//  - L4 keeps the plain MODE-1 epilogue (R13 lesson: adding shfl+atomic
//    reduction to the heavy tanh-expansion epilogue cost +6us net).
//  - rownorm stays hidden in the L5 dispatch as extra blocks (R12-proven).
//  - dot/nrm computed in L5's light MODE-2 epilogue via shfl+atomicAdd
//    (R13-proven correct) -> stats5_k and its 8MB Y5 re-read are gone.
//  - transW z=6 slice zeroes dotv/nrmv each replay (atomic accumulators).
// 13 dispatches. Best-known: R12 235.3us.
// Locked lessons:
//  - R5: __threadfence split-K fusion = 4x loss (per-XCD L2 wb/inv).
//  - R8: grids < ~1.5 blocks/CU are latency-starved (64x128 tile: 312us).
//  - R9: >4 in-flight uint4 prefetch regs spill (WRITE_SIZE 116MB).
//  - R10: 32x64 tile halves MFMA:LDS ratio -> 251us. 64x64 optimum.
//  - R11: replicated per-block rank loops beat dispatch savings.
//  - R13: fuse reductions into LIGHT epilogues only (MODE 2, not MODE 1).

using s8v = __attribute__((ext_vector_type(8))) short;
using f4v = __attribute__((ext_vector_type(4))) float;

__device__ __forceinline__ float bf2f(short b) {
  unsigned u = ((unsigned)(unsigned short)b) << 16;
  return __builtin_bit_cast(float, u);
}
__device__ __forceinline__ short f2bf(float f) {
  unsigned u = __builtin_bit_cast(unsigned, f);
  u = (u + 0x7FFFu + ((u >> 16) & 1u)) >> 16;
  return (short)u;
}
__device__ __forceinline__ void split_store(float f, short* hi, short* lo) {
  short h = f2bf(f);
  *hi = h;
  *lo = f2bf(f - bf2f(h));
}

// Transpose+split all six W (1024 x N fp32) -> (N x 1024 bf16 hi/lo).
// z==6 slice: pack x into hi/lo bf16 (blocks 0-127) + zero dotv/nrmv
// (blocks 128+; re-zeroed in-stream every graph replay).
struct TWArgs {
  const float* W[6];
  short* Th[6];
  short* Tl[6];
};
__global__ void __launch_bounds__(256)
transW_all(TWArgs a, const float* __restrict__ x, short* __restrict__ A0h,
           short* __restrict__ A0l, float4* __restrict__ zreg) {
  __shared__ float tile[64][65];
  const int t = threadIdx.x;
  if (blockIdx.z == 6) {
    const int bf = blockIdx.y * 16 + blockIdx.x;
    if (bf < 128) {
      int i = (bf * 256 + t) * 4;
      float4 v = *(const float4*)&x[i];
      short4 h, l;
      h.x = f2bf(v.x); l.x = f2bf(v.x - bf2f(h.x));
      h.y = f2bf(v.y); l.y = f2bf(v.y - bf2f(h.y));
      h.z = f2bf(v.z); l.z = f2bf(v.z - bf2f(h.z));
      h.w = f2bf(v.w); l.w = f2bf(v.w - bf2f(h.w));
      *(short4*)&A0h[i] = h;
      *(short4*)&A0l[i] = l;
    } else {
      int flat = (bf - 128) * 256 + t;
      if (flat < 1984) {  // 31744 B: dotv + nrmv (3968 f32 each)
        float4 zz = {0.f, 0.f, 0.f, 0.f};
        zreg[flat] = zz;
      }
    }
    return;
  }
  const int z = blockIdx.z;
  const int N = (z == 5) ? 512 : 1024;
  const int n0 = blockIdx.x * 64, k0 = blockIdx.y * 64;
  if (n0 >= N) return;
  const float* __restrict__ W = a.W[z];
  short* __restrict__ Th = a.Th[z];
  short* __restrict__ Tl = a.Tl[z];
  const int r = t >> 4, c4 = (t & 15) * 4;
#pragma unroll
  for (int i = 0; i < 4; ++i) {
    int rr = r + 16 * i;
    float4 v = *(const float4*)&W[(size_t)(k0 + rr) * N + n0 + c4];
    tile[rr][c4 + 0] = v.x;
    tile[rr][c4 + 1] = v.y;
    tile[rr][c4 + 2] = v.z;
    tile[rr][c4 + 3] = v.w;
  }
  __syncthreads();
#pragma unroll
  for (int i = 0; i < 4; ++i) {
    int n = r + 16 * i;
    short4 h, l;
    float f0 = tile[c4 + 0][n], f1 = tile[c4 + 1][n];
    float f2 = tile[c4 + 2][n], f3 = tile[c4 + 3][n];
    h.x = f2bf(f0); l.x = f2bf(f0 - bf2f(h.x));
    h.y = f2bf(f1); l.y = f2bf(f1 - bf2f(h.y));
    h.z = f2bf(f2); l.z = f2bf(f2 - bf2f(h.z));
    h.w = f2bf(f3); l.w = f2bf(f3 - bf2f(h.w));
    size_t o = (size_t)(n0 + n) * 1024 + k0 + c4;
    *(short4*)&Th[o] = h;
    *(short4*)&Tl[o] = l;
  }
}

// ------------------------------------------------------------- MFMA GEMM ----
// R7 body: block tile 64x64, 4 waves 2x2, wave tile 32x32 (12 MFMA/stage),
// BK=32, BKP=40 pad (<=2-way LDS conflicts = free), register prefetch.
// MODE 1: fused epilogue rows b*Dn+1+2u / +2+2u = tanh(bias -/+ acc), plus
//         zero row tanh(bias) at u==0. (hi/lo bf16 out; NO reductions)
// MODE 2: raw fp32 out + dot(bias,row)/||row||^2 atomics (aux0/aux1).
// MODE 3: split-K partial: Of[(bz*R + rr)*N + col] = acc.
template <int MODE, int D, int KS>
__device__ __forceinline__ void gemm_body(
    int bx, int by, int bz, int R, const short* __restrict__ Ah,
    const short* __restrict__ Al, const short* __restrict__ Bh,
    const short* __restrict__ Bl, const float* __restrict__ bias,
    short* __restrict__ Oh, short* __restrict__ Ol, float* __restrict__ Of,
    float* __restrict__ aux0, float* __restrict__ aux1, int N, int Dn) {
  constexpr int KC = 1024 / KS;
  constexpr int BKP = 40;
  __shared__ short As_h[64 * BKP], As_l[64 * BKP];
  __shared__ short Bs_h[64 * BKP], Bs_l[64 * BKP];
  const int t = threadIdx.x;
  const int row0 = by * 64;
  const int col0 = bx * 64;
  const int kb = bz * KC;
  const int sr = t >> 2, sko = (t & 3) * 8;
  const short* Ahp = Ah + (size_t)(row0 + sr) * 1024 + kb + sko;
  const short* Alp = Al + (size_t)(row0 + sr) * 1024 + kb + sko;
  const short* Bhp = Bh + (size_t)(col0 + sr) * 1024 + kb + sko;
  const short* Blp = Bl + (size_t)(col0 + sr) * 1024 + kb + sko;
  const int w = t >> 6, lane = t & 63;
  const int l16 = lane & 15, q = lane >> 4;
  const int wm0 = (w & 1) * 32, wn0 = (w >> 1) * 32;
  const int abase = (wm0 + l16) * BKP + q * 8;
  const int bbase = (wn0 + l16) * BKP + q * 8;
  f4v acc[2][2];
#pragma unroll
  for (int i = 0; i < 2; ++i)
#pragma unroll
    for (int j = 0; j < 2; ++j) acc[i][j] = (f4v){0.f, 0.f, 0.f, 0.f};
  uint4 rah = *(const uint4*)(Ahp);
  uint4 ral = *(const uint4*)(Alp);
  uint4 rbh = *(const uint4*)(Bhp);
  uint4 rbl = *(const uint4*)(Blp);
  for (int k0 = 0; k0 < KC; k0 += 32) {
    __syncthreads();
    *(uint4*)&As_h[sr * BKP + sko] = rah;
    *(uint4*)&As_l[sr * BKP + sko] = ral;
    *(uint4*)&Bs_h[sr * BKP + sko] = rbh;
    *(uint4*)&Bs_l[sr * BKP + sko] = rbl;
    if (k0 + 32 < KC) {  // prefetch next slab; waits land before next LDS-write
      rah = *(const uint4*)(Ahp + k0 + 32);
      ral = *(const uint4*)(Alp + k0 + 32);
      rbh = *(const uint4*)(Bhp + k0 + 32);
      rbl = *(const uint4*)(Blp + k0 + 32);
    }
    __syncthreads();
    s8v ah[2], al[2], bh[2], bl[2];
#pragma unroll
    for (int mt = 0; mt < 2; ++mt) {
      ah[mt] = *(const s8v*)&As_h[abase + mt * 16 * BKP];
      al[mt] = *(const s8v*)&As_l[abase + mt * 16 * BKP];
    }
#pragma unroll
    for (int nt = 0; nt < 2; ++nt) {
      bh[nt] = *(const s8v*)&Bs_h[bbase + nt * 16 * BKP];
      bl[nt] = *(const s8v*)&Bs_l[bbase + nt * 16 * BKP];
    }
#pragma unroll
    for (int mt = 0; mt < 2; ++mt)
#pragma unroll
      for (int nt = 0; nt < 2; ++nt) {
        acc[mt][nt] = __builtin_amdgcn_mfma_f32_16x16x32_bf16(
            ah[mt], bh[nt], acc[mt][nt], 0, 0, 0);
        acc[mt][nt] = __builtin_amdgcn_mfma_f32_16x16x32_bf16(
            ah[mt], bl[nt], acc[mt][nt], 0, 0, 0);
        acc[mt][nt] = __builtin_amdgcn_mfma_f32_16x16x32_bf16(
            al[mt], bh[nt], acc[mt][nt], 0, 0, 0);
      }
  }

  if (MODE == 2) {
    // L5: raw fp32 out + dot(b5,row)/||row||^2 atomics (aux0/aux1).
    const float bc0 = bias[col0 + wn0 + l16];
    const float bc1 = bias[col0 + wn0 + 16 + l16];
#pragma unroll
    for (int mt = 0; mt < 2; ++mt) {
#pragma unroll
      for (int r = 0; r < 4; ++r) {
        const int rr = row0 + wm0 + mt * 16 + q * 4 + r;
        float sd = 0.f, sn = 0.f;
#pragma unroll
        for (int nt = 0; nt < 2; ++nt) {
          const int gcol = col0 + wn0 + nt * 16 + l16;
          const float bc = nt ? bc1 : bc0;
          const float v = acc[mt][nt][r];
          Of[(size_t)rr * N + gcol] = v;
          sd = fmaf(bc, v, sd);
          sn = fmaf(v, v, sn);
        }
#pragma unroll
        for (int d = 1; d < 16; d <<= 1) {
          sd += __shfl_xor(sd, d);
          sn += __shfl_xor(sn, d);
        }
        if (l16 == 0) {
          atomicAdd(&aux0[rr], sd);
          atomicAdd(&aux1[rr], sn);
        }
      }
    }
    return;
  }

#pragma unroll
  for (int nt = 0; nt < 2; ++nt) {
    int gcol = col0 + wn0 + nt * 16 + l16;
    float bc = (MODE == 1) ? bias[gcol] : 0.f;
#pragma unroll
    for (int mt = 0; mt < 2; ++mt) {
#pragma unroll
      for (int r = 0; r < 4; ++r) {
        float v = acc[mt][nt][r];
        int rr = row0 + wm0 + mt * 16 + q * 4 + r;
        if (MODE == 1) {
          int b = rr / D, u = rr - b * D;
          size_t ob = (size_t)(b * Dn) * N + gcol;
          size_t om = ob + (size_t)(1 + 2 * u) * N;
          size_t op = ob + (size_t)(2 + 2 * u) * N;
          split_store(tanhf(bc - v), &Oh[om], &Ol[om]);
          split_store(tanhf(bc + v), &Oh[op], &Ol[op]);
          if (u == 0) split_store(tanhf(bc), &Oh[ob], &Ol[ob]);
        } else {
          Of[((size_t)bz * R + rr) * N + gcol] = v;
        }
      }
    }
  }
}

template <int MODE, int D, int KS>
__global__ void __launch_bounds__(256, 2)
mfma_gemm(const short* __restrict__ Ah, const short* __restrict__ Al,
          const short* __restrict__ Bh, const short* __restrict__ Bl,
          const float* __restrict__ bias, short* __restrict__ Oh,
          short* __restrict__ Ol, float* __restrict__ Of,
          float* __restrict__ aux0, float* __restrict__ aux1, int N, int Dn) {
  gemm_body<MODE, D, KS>(blockIdx.x, blockIdx.y, blockIdx.z,
                         (int)gridDim.y << 6, Ah, Al, Bh, Bl, bias, Oh, Ol,
                         Of, aux0, aux1, N, Dn);
}

// Row sum-of-squares of one C5 row from hi/lo (R4's exact order).
__device__ __forceinline__ void rownorm_body(const short* __restrict__ hi,
                                             const short* __restrict__ lo,
                                             float* __restrict__ ns, int row) {
  int t = threadIdx.x;
  size_t base = (size_t)row * 1024 + t * 4;
  short4 h = *(const short4*)&hi[base];
  short4 l = *(const short4*)&lo[base];
  float v0 = bf2f(h.x) + bf2f(l.x);
  float v1 = bf2f(h.y) + bf2f(l.y);
  float v2 = bf2f(h.z) + bf2f(l.z);
  float v3 = bf2f(h.w) + bf2f(l.w);
  float s = v0 * v0 + v1 * v1 + v2 * v2 + v3 * v3;
  __shared__ float red[256];
  red[t] = s;
  __syncthreads();
  for (int off = 128; off; off >>= 1) {
    if (t < off) red[t] += red[t + off];
    __syncthreads();
  }
  if (t == 0) ns[row] = red[0];
}

// Merged L5 GEMM (496 blocks, 64x64 body, MODE-2 epilogue with dot/nrm
// atomics) + rownorm (3968 blocks). GEMM/rownorm both only READ C5;
// writes (Y5+dotv+nrmv vs ns) disjoint.
__global__ void __launch_bounds__(256, 2)
gemm5_rownorm(const short* __restrict__ C5h, const short* __restrict__ C5l,
              const short* __restrict__ W5h, const short* __restrict__ W5l,
              const float* __restrict__ b5, float* __restrict__ Y5,
              float* __restrict__ ns, float* __restrict__ dotv,
              float* __restrict__ nrmv) {
  const int bid = blockIdx.x;
  if (bid < 496) {
    gemm_body<2, 31, 1>(bid & 7, bid >> 3, 0, 0, C5h, C5l, W5h, W5l, b5,
                        nullptr, nullptr, Y5, dotv, nrmv, 512, 0);
  } else {
    rownorm_body(C5h, C5l, ns, bid - 496);
  }
}

// Combine split-K partials, layer 0: out = tanh(bias + sum) -> hi/lo.
template <int KS>
__global__ void __launch_bounds__(256)
comb0_hl(const float* __restrict__ P, const float* __restrict__ bias,
         short* __restrict__ Oh, short* __restrict__ Ol, int R, int N) {
  int i = blockIdx.x * 256 + threadIdx.x;
  int n4 = N >> 2;
  int r = i / n4, c4 = (i - r * n4) * 4;
  float4 y = *(const float4*)&P[(size_t)r * N + c4];
  size_t stride = (size_t)R * N;
#pragma unroll
  for (int ks = 1; ks < KS; ++ks) {
    const float4 p = *(const float4*)&P[ks * stride + (size_t)r * N + c4];
    y.x += p.x; y.y += p.y; y.z += p.z; y.w += p.w;
  }
  float4 bc = *(const float4*)(bias + c4);
  float t0 = tanhf(bc.x + y.x), t1 = tanhf(bc.y + y.y);
  float t2 = tanhf(bc.z + y.z), t3 = tanhf(bc.w + y.w);
  short4 h, l;
  h.x = f2bf(t0); l.x = f2bf(t0 - bf2f(h.x));
  h.y = f2bf(t1); l.y = f2bf(t1 - bf2f(h.y));
  h.z = f2bf(t2); l.z = f2bf(t2 - bf2f(h.z));
  h.w = f2bf(t3); l.w = f2bf(t3 - bf2f(h.w));
  *(short4*)&Oh[(size_t)r * N + c4] = h;
  *(short4*)&Ol[(size_t)r * N + c4] = l;
}

// Combine split-K partials, layers 1..3: rows b*Dn+1+2u (tanh(b-y)) and
// b*Dn+2+2u (tanh(b+y)); zero row tanh(b) at u==0. hi/lo out.
template <int KS, int D>
__global__ void __launch_bounds__(256)
comb1_hl(const float* __restrict__ P, const float* __restrict__ bias,
         short* __restrict__ Oh, short* __restrict__ Ol, int R, int N,
         int Dn) {
  int i = blockIdx.x * 256 + threadIdx.x;
  int n4 = N >> 2;
  int r = i / n4, c4 = (i - r * n4) * 4;
  int b = r / D, u = r - b * D;
  float4 y = *(const float4*)&P[(size_t)r * N + c4];
  size_t stride = (size_t)R * N;
#pragma unroll
  for (int ks = 1; ks < KS; ++ks) {
    const float4 p = *(const float4*)&P[ks * stride + (size_t)r * N + c4];
    y.x += p.x; y.y += p.y; y.z += p.z; y.w += p.w;
  }
  float4 bc = *(const float4*)(bias + c4);
  size_t ob = (size_t)(b * Dn) * N + c4;
  size_t om = ob + (size_t)(1 + 2 * u) * N;
  size_t op = ob + (size_t)(2 + 2 * u) * N;
  {
    float t0 = tanhf(bc.x - y.x), t1 = tanhf(bc.y - y.y);
    float t2 = tanhf(bc.z - y.z), t3 = tanhf(bc.w - y.w);
    short4 h, l;
    h.x = f2bf(t0); l.x = f2bf(t0 - bf2f(h.x));
    h.y = f2bf(t1); l.y = f2bf(t1 - bf2f(h.y));
    h.z = f2bf(t2); l.z = f2bf(t2 - bf2f(h.z));
    h.w = f2bf(t3); l.w = f2bf(t3 - bf2f(h.w));
    *(short4*)&Oh[om] = h;
    *(short4*)&Ol[om] = l;
  }
  {
    float t0 = tanhf(bc.x + y.x), t1 = tanhf(bc.y + y.y);
    float t2 = tanhf(bc.z + y.z), t3 = tanhf(bc.w + y.w);
    short4 h, l;
    h.x = f2bf(t0); l.x = f2bf(t0 - bf2f(h.x));
    h.y = f2bf(t1); l.y = f2bf(t1 - bf2f(h.y));
    h.z = f2bf(t2); l.z = f2bf(t2 - bf2f(h.z));
    h.w = f2bf(t3); l.w = f2bf(t3 - bf2f(h.w));
    *(short4*)&Oh[op] = h;
    *(short4*)&Ol[op] = l;
  }
  if (u == 0) {
    float t0 = tanhf(bc.x), t1 = tanhf(bc.y);
    float t2 = tanhf(bc.z), t3 = tanhf(bc.w);
    short4 h, l;
    h.x = f2bf(t0); l.x = f2bf(t0 - bf2f(h.x));
    h.y = f2bf(t1); l.y = f2bf(t1 - bf2f(h.y));
    h.z = f2bf(t2); l.z = f2bf(t2 - bf2f(h.z));
    h.w = f2bf(t3); l.w = f2bf(t3 - bf2f(h.w));
    *(short4*)&Oh[ob] = h;
    *(short4*)&Ol[ob] = l;
  }
}

// Merged prune: per-batch 243->128 (layer-4 classes) then 384->128 (final).
// ||b5||^2 computed in-block (R4 stats5's exact reduction order).
__global__ void __launch_bounds__(384)
prune45_k(const float* __restrict__ ns, const float* __restrict__ dotv,
          const float* __restrict__ nrmv, const float* __restrict__ b5,
          int* __restrict__ kept4, int* __restrict__ kept5) {
  const int b = blockIdx.x, t = threadIdx.x;
  __shared__ float nss[31];
  __shared__ float rb[256];
  __shared__ float keyA[243];
  __shared__ int cls[243];
  __shared__ int k4s[128];
  __shared__ float pns[128];
  __shared__ float keyB[384];
  if (t < 31) nss[t] = ns[b * 31 + t];
  if (t < 256) {
    float a = b5[t], c = b5[t + 256];
    rb[t] = fmaf(a, a, 0.f);
    rb[t] = fmaf(c, c, rb[t]);
  }
  __syncthreads();
  for (int off = 128; off; off >>= 1) {
    if (t < off) rb[t] += rb[t + off];
    __syncthreads();
  }
  const float nb5 = rb[0];
  if (t < 243) {
    int j = t / 3, t4 = t - 3 * j;
    int d0 = j / 27, d1 = (j / 9) % 3, d2 = (j / 3) % 3, d3 = j % 3;
    int u = 0;
    u = (d0 == 1) ? 0 : (1 + 2 * u + (d0 == 2));
    u = (d1 == 1) ? 0 : (1 + 2 * u + (d1 == 2));
    u = (d2 == 1) ? 0 : (1 + 2 * u + (d2 == 2));
    u = (d3 == 1) ? 0 : (1 + 2 * u + (d3 == 2));
    cls[t] = u;
    keyA[t] = (t4 == 1) ? 0.f : nss[u];
  }
  __syncthreads();
  if (t < 243) {
    float k = keyA[t];
    int rank = 0;
    for (int e = 0; e < 243; ++e) {
      float ke = keyA[e];
      rank += (ke > k) || (ke == k && e < t);
    }
    if (rank < 128) {
      int t4 = t - 3 * (t / 3);
      int kv = (cls[t] << 1) | (t4 == 2 ? 1 : 0);
      k4s[rank] = kv;
      kept4[b * 128 + rank] = kv;
    }
  }
  __syncthreads();
  if (t < 128) {
    int k4 = k4s[t];
    int c = k4 >> 1;
    float s = (k4 & 1) ? 1.f : -1.f;
    pns[t] = nb5 + nrmv[b * 31 + c] + s * 2.f * dotv[b * 31 + c];
  }
  __syncthreads();
  const int m = t / 3, tt = t - 3 * m;
  keyB[t] = (tt == 1) ? 0.f : pns[m];
  __syncthreads();
  float k = keyB[t];
  int rank = 0;
  for (int e = 0; e < 384; ++e) {
    float ke = keyB[e];
    rank += (ke > k) || (ke == k && e < t);
  }
  if (rank < 128) kept5[b * 128 + rank] = (m << 1) | (tt == 2 ? 1 : 0);
}

// Final data (B,512,128) + argmax-|.| output (B,512).
__global__ void __launch_bounds__(256)
finalize_k(const float* __restrict__ Y5, const float* __restrict__ b5,
           const int* __restrict__ kept4, const int* __restrict__ kept5,
           float* __restrict__ out, float* __restrict__ dataout) {
  const int b = blockIdx.y;
  const int o0 = blockIdx.x * 64;
  __shared__ float Ys[31][65];
  __shared__ float bias_s[64];
  __shared__ float vt[64][130];
  __shared__ float ra[64][4];
  __shared__ float rv[64][4];
  const int t = threadIdx.x;
  for (int idx = t; idx < 31 * 64; idx += 256) {
    int c = idx >> 6, o = idx & 63;
    Ys[c][o] = Y5[((size_t)b * 31 + c) * 512 + o0 + o];
  }
  if (t < 64) bias_s[t] = b5[o0 + t];
  const int rr = t & 127, oh = t >> 7;
  int k5 = kept5[b * 128 + rr];
  int m = k5 >> 1;
  float sig = (k5 & 1) ? 1.f : -1.f;
  int k4 = kept4[b * 128 + m];
  int cc = k4 >> 1;
  float s4 = (k4 & 1) ? 1.f : -1.f;
  float afac = sig * s4;
  __syncthreads();
#pragma unroll
  for (int ol = 0; ol < 32; ++ol) {
    int o = oh * 32 + ol;
    float v = sig * bias_s[o] + afac * Ys[cc][o];
    dataout[((size_t)b * 512 + o0 + o) * 128 + rr] = v;
    vt[o][rr] = v;
  }
  __syncthreads();
  int o = t >> 2, q = t & 3;
  float bestv = vt[o][q * 32];
  float besta = fabsf(bestv);
  for (int i = 1; i < 32; ++i) {
    float v = vt[o][q * 32 + i];
    float a = fabsf(v);
    if (a > besta) {
      besta = a;
      bestv = v;
    }
  }
  ra[o][q] = besta;
  rv[o][q] = bestv;
  __syncthreads();
  if (t < 64) {
    float ba = ra[t][0], bv = rv[t][0];
#pragma unroll
    for (int qq = 1; qq < 4; ++qq) {
      if (ra[t][qq] > ba) {
        ba = ra[t][qq];
        bv = rv[t][qq];
      }
    }
    out[(size_t)b * 512 + o0 + t] = bv;
  }
}

extern "C" void kernel_launch(void* const* d_in, const int* in_sizes, int n_in,
                              void* d_out, int out_size, void* d_ws,
                              size_t ws_size, hipStream_t stream) {
  const float* x = (const float*)d_in[0];
  const float* Wt[6];
  const float* bs[6];
  for (int i = 0; i < 6; ++i) {
    Wt[i] = (const float*)d_in[1 + 2 * i];
    bs[i] = (const float*)d_in[2 + 2 * i];
  }
  char* base = (char*)d_ws;
  // Byte-offset layout. Lifetime-disjoint aliases:
  //   PA (split-K partials L0-L2) over C4h/C4l (written first at L3-comb);
  //     L0/L1 KS=8 partials = 4 MB, L2 KS=4 = 6.3 MB, region is 7.86 MB.
  //   PB (split-K partials L3)    over W0/W1   (dead after L1)
  //   C5h over W0..W1, C5l over W2..W3 (dead after L3)
  //   Y5 over C1..C4 (dead after L4)
  short* A0h = (short*)(base + 0);
  short* A0l = (short*)(base + 262144);
  short* Wh[6], *Wl[6];
  {
    size_t off = 524288;
    for (int i = 0; i < 6; ++i) {
      size_t sz = (i < 5) ? 2097152 : 1048576;
      Wh[i] = (short*)(base + off);
      Wl[i] = (short*)(base + off + sz);
      off += 2 * sz;
    }
  }
  short* C1h = (short*)(base + 23592960), *C1l = (short*)(base + 23855104);
  short* C2h = (short*)(base + 24117248), *C2l = (short*)(base + 24903680);
  short* C3h = (short*)(base + 25690112), *C3l = (short*)(base + 27525120);
  short* C4h = (short*)(base + 29360128), *C4l = (short*)(base + 33292288);
  short* C5h = (short*)(base + 524288);
  short* C5l = (short*)(base + 8912896);
  float* PA = (float*)(base + 29360128);  // L0/L1 KS=8: 4 MB; L2 KS=4: 6.3 MB
  float* PB = (float*)(base + 524288);    // 7.34 MB (L3 KS=2)
  float* Y5 = (float*)(base + 23592960);
  // Zero region (cleared each replay by transW_all z==6 slice): dotv+nrmv.
  char* zb = base + 37224448;
  float* dotv = (float*)zb;               // 3968 f32 (atomic)
  float* nrmv = (float*)(zb + 15872);     // 3968 f32 (atomic)
  float* ns = (float*)(zb + 31744);       // 3968 f32 (written whole, no zero)
  int* kept4 = (int*)(zb + 47616);
  int* kept5 = (int*)(zb + 113152);
  float* outp = (float*)d_out;
  float* dataout = outp + 128 * 512;

  dim3 blk(256);
  TWArgs twa;
  for (int i = 0; i < 6; ++i) {
    twa.W[i] = Wt[i];
    twa.Th[i] = Wh[i];
    twa.Tl[i] = Wl[i];
  }
  // Transpose W + pack x + zero dotv/nrmv, one launch.
  transW_all<<<dim3(16, 16, 7), blk, 0, stream>>>(twa, x, A0h, A0l,
                                                  (float4*)zb);
  // L0: x -> C1 (split-K 8, 256 blocks)
  mfma_gemm<3, 1, 8><<<dim3(16, 2, 8), blk, 0, stream>>>(
      A0h, A0l, Wh[0], Wl[0], nullptr, nullptr, nullptr, PA, nullptr, nullptr,
      1024, 0);
  comb0_hl<8><<<dim3(128), blk, 0, stream>>>(PA, bs[0], C1h, C1l, 128, 1024);
  // L1: C1 -> C2 (split-K 8, 256 blocks)
  mfma_gemm<3, 1, 8><<<dim3(16, 2, 8), blk, 0, stream>>>(
      C1h, C1l, Wh[1], Wl[1], nullptr, nullptr, nullptr, PA, nullptr, nullptr,
      1024, 0);
  comb1_hl<8, 1><<<dim3(128), blk, 0, stream>>>(PA, bs[1], C2h, C2l, 128, 1024,
                                                3);
  // L2: C2 (384) -> C3 (split-K 4)
  mfma_gemm<3, 3, 4><<<dim3(16, 6, 4), blk, 0, stream>>>(
      C2h, C2l, Wh[2], Wl[2], nullptr, nullptr, nullptr, PA, nullptr, nullptr,
      1024, 0);
  comb1_hl<4, 3><<<dim3(384), blk, 0, stream>>>(PA, bs[2], C3h, C3l, 384, 1024,
                                                7);
  // L3: C3 (896) -> C4 (split-K 2, partials over dead W0/W1)
  mfma_gemm<3, 7, 2><<<dim3(16, 14, 2), blk, 0, stream>>>(
      C3h, C3l, Wh[3], Wl[3], nullptr, nullptr, nullptr, PB, nullptr, nullptr,
      1024, 0);
  comb1_hl<2, 7><<<dim3(896), blk, 0, stream>>>(PB, bs[3], C4h, C4l, 896, 1024,
                                                15);
  // L4: C4 (1920) -> C5 (3968), fused epilogue (no reductions)
  mfma_gemm<1, 15, 1><<<dim3(16, 30), blk, 0, stream>>>(
      C4h, C4l, Wh[4], Wl[4], bs[4], C5h, C5l, nullptr, nullptr, nullptr, 1024,
      31);
  // L5 GEMM (496 blocks, + dot/nrm atomics) + rownorm (3968 blocks)
  gemm5_rownorm<<<dim3(496 + 3968), blk, 0, stream>>>(
      C5h, C5l, Wh[5], Wl[5], bs[5], Y5, ns, dotv, nrmv);
  // Merged prune (243->128 then 384->128, per batch)
  prune45_k<<<dim3(128), dim3(384), 0, stream>>>(ns, dotv, nrmv, bs[5], kept4,
                                                 kept5);
  finalize_k<<<dim3(8, 128), blk, 0, stream>>>(Y5, bs[5], kept4, kept5, outp,
                                               dataout);
}